// Round 1
// baseline (1408.413 us; speedup 1.0000x reference)
//
#include <hip/hip_runtime.h>
#include <hip/hip_bf16.h>

// Qwen3 MoE sparse block, MI355X.
// Memory-bound on fp32 expert weights (1.21 GB -> ~192us floor @6.3TB/s).
// Router in exact fp32 (top-k stability); expert GEMMs bf16 MFMA 16x16x32.

#define NTOK 512
#define HDIM 2048
#define IDIM 768
#define NEXP 64
#define TOPK 8
#define CAP  256

typedef short short8 __attribute__((ext_vector_type(8)));
typedef float floatx4 __attribute__((ext_vector_type(4)));

__device__ __forceinline__ unsigned short bf16_bits(float f) {
    union { float f; unsigned int u; } v; v.f = f;
    unsigned int r = (v.u + 0x7FFFu + ((v.u >> 16) & 1u)) >> 16;
    return (unsigned short)r;
}

__device__ __forceinline__ short8 pack_bf16x8(float4 f0, float4 f1) {
    short8 r;
    r[0] = (short)bf16_bits(f0.x); r[1] = (short)bf16_bits(f0.y);
    r[2] = (short)bf16_bits(f0.z); r[3] = (short)bf16_bits(f0.w);
    r[4] = (short)bf16_bits(f1.x); r[5] = (short)bf16_bits(f1.y);
    r[6] = (short)bf16_bits(f1.z); r[7] = (short)bf16_bits(f1.w);
    return r;
}

// ---------------- Router: logits + softmax + top8 + dispatch gather ----------
__global__ __launch_bounds__(256) void router_kernel(
    const float* __restrict__ x, const float* __restrict__ gw,
    float* __restrict__ dout,            // full d_out; logits at offset NTOK*HDIM
    int* __restrict__ cnt, int* __restrict__ tok_map, float* __restrict__ w_map,
    unsigned short* __restrict__ xb)
{
    const int t = blockIdx.x;
    const int tid = threadIdx.x;
    const int lane = tid & 63, wave = tid >> 6;

    __shared__ __align__(16) float xs[HDIM];
    __shared__ __align__(16) unsigned short xbs[HDIM];
    __shared__ float lg[NEXP];
    __shared__ int   sel_sh[TOPK];
    __shared__ int   slot_sh[TOPK];

    for (int i = tid; i < HDIM; i += 256) {
        float v = x[(size_t)t * HDIM + i];
        xs[i] = v;
        xbs[i] = bf16_bits(v);
    }
    __syncthreads();

    float* logits_out = dout + (size_t)NTOK * HDIM;
    // each wave handles 16 experts
    for (int e = wave; e < NEXP; e += 4) {
        const float* gr = gw + (size_t)e * HDIM;
        float s = 0.f;
        for (int k = lane; k < HDIM; k += 64) s += xs[k] * gr[k];
        for (int off = 32; off; off >>= 1) s += __shfl_xor(s, off);
        if (lane == 0) { lg[e] = s; logits_out[(size_t)t * NEXP + e] = s; }
    }
    __syncthreads();

    if (wave == 0) {
        // fp32 softmax over 64 experts; lane e holds expert e
        float l = lg[lane];
        float m = l;
        for (int off = 32; off; off >>= 1) m = fmaxf(m, __shfl_xor(m, off));
        float ex = expf(l - m);
        float sum = ex;
        for (int off = 32; off; off >>= 1) sum += __shfl_xor(sum, off);
        float prob = ex / sum;

        // iterative top-8 (butterfly argmax, lowest-index tie-break = stable)
        float v = prob;
        float myw = 0.f; int mysel = -1;
        #pragma unroll
        for (int j = 0; j < TOPK; j++) {
            float bv = v; int bi = lane;
            for (int off = 32; off; off >>= 1) {
                float ov = __shfl_xor(bv, off);
                int   oi = __shfl_xor(bi, off);
                if (ov > bv || (ov == bv && oi < bi)) { bv = ov; bi = oi; }
            }
            if (lane == j) { myw = bv; mysel = bi; }
            if (lane == bi) v = -1.0f;
        }
        float t8 = (lane < TOPK) ? myw : 0.f;
        for (int off = 32; off; off >>= 1) t8 += __shfl_xor(t8, off);
        if (lane < TOPK) {
            float rw = myw / t8;                       // renormalized routing weight
            int slot = atomicAdd(&cnt[mysel], 1);      // order-independent (no drops)
            sel_sh[lane] = mysel; slot_sh[lane] = slot;
            if (slot < CAP) {
                tok_map[mysel * CAP + slot] = t;
                w_map[mysel * CAP + slot] = rw;
            }
        }
    }
    __syncthreads();

    // dispatch: copy bf16 row to each selected expert's slot (256 x 16B = 4KB)
    const uint4* src = reinterpret_cast<const uint4*>(xbs);
    #pragma unroll
    for (int j = 0; j < TOPK; j++) {
        int e = sel_sh[j], slot = slot_sh[j];
        if (slot >= CAP) continue;
        uint4* dst = reinterpret_cast<uint4*>(xb + ((size_t)e * CAP + slot) * HDIM);
        dst[tid] = src[tid];
    }
}

// ------------- Stage A: g = xb@w1^T, u = xb@w3^T, act = silu(g)*u -----------
// grid (12, 64): blockIdx.x = 64-wide N-tile of IDIM, blockIdx.y = expert.
// 4 waves: wave w owns N columns [nt0+16w, nt0+16w+16), ALL M rows (<=256).
// A staged in LDS (shared), weight frags streamed global->reg (read once).
__global__ __launch_bounds__(256) void expert_gu_kernel(
    const unsigned short* __restrict__ xb, const float* __restrict__ w1,
    const float* __restrict__ w3, const int* __restrict__ cnt,
    unsigned short* __restrict__ act)
{
    const int e = blockIdx.y;
    int count = cnt[e]; if (count > CAP) count = CAP;
    if (count == 0) return;
    const int nt0 = blockIdx.x * 64;
    const int tid = threadIdx.x;
    const int lane = tid & 63, wave = tid >> 6;
    const int nl = lane & 15, quad = lane >> 4;

    __shared__ __align__(16) unsigned short a_lds[CAP * 40];  // 32 cols + 8 pad

    floatx4 acc_g[16], acc_u[16];
    #pragma unroll
    for (int i = 0; i < 16; i++) { acc_g[i] = (floatx4)(0.f); acc_u[i] = (floatx4)(0.f); }

    const unsigned short* Abase = xb + (size_t)e * CAP * HDIM;
    const int nrow = nt0 + wave * 16 + nl;
    const float* B1 = w1 + (size_t)e * IDIM * HDIM + (size_t)nrow * HDIM;
    const float* B3 = w3 + (size_t)e * IDIM * HDIM + (size_t)nrow * HDIM;

    const int srow = tid >> 2;          // staging: 4 threads per row
    const int scol = (tid & 3) * 8;     // 8 bf16 = 16B per thread

    for (int k0 = 0; k0 < HDIM; k0 += 32) {
        #pragma unroll
        for (int p = 0; p < 4; p++) {
            int r = srow + p * 64;
            uint4 val = (r < count)
                ? *reinterpret_cast<const uint4*>(Abase + (size_t)r * HDIM + k0 + scol)
                : make_uint4(0u, 0u, 0u, 0u);
            *reinterpret_cast<uint4*>(&a_lds[r * 40 + scol]) = val;
        }
        const float* b1p = B1 + k0 + quad * 8;
        const float* b3p = B3 + k0 + quad * 8;
        float4 a0 = *reinterpret_cast<const float4*>(b1p);
        float4 a1 = *reinterpret_cast<const float4*>(b1p + 4);
        float4 c0 = *reinterpret_cast<const float4*>(b3p);
        float4 c1 = *reinterpret_cast<const float4*>(b3p + 4);
        short8 bf1 = pack_bf16x8(a0, a1);
        short8 bf3 = pack_bf16x8(c0, c1);
        __syncthreads();
        #pragma unroll
        for (int mb = 0; mb < 16; mb++) {
            if (mb * 16 < count) {
                short8 af = *reinterpret_cast<const short8*>(&a_lds[(mb * 16 + nl) * 40 + quad * 8]);
                acc_g[mb] = __builtin_amdgcn_mfma_f32_16x16x32_bf16(af, bf1, acc_g[mb], 0, 0, 0);
                acc_u[mb] = __builtin_amdgcn_mfma_f32_16x16x32_bf16(af, bf3, acc_u[mb], 0, 0, 0);
            }
        }
        __syncthreads();
    }

    // epilogue: silu(g)*u -> bf16 act. C/D layout: col=lane&15, row=quad*4+r
    const int colg = nt0 + wave * 16 + nl;
    #pragma unroll
    for (int mb = 0; mb < 16; mb++) {
        if (mb * 16 >= count) break;
        #pragma unroll
        for (int r = 0; r < 4; r++) {
            int row = mb * 16 + quad * 4 + r;
            if (row < count) {
                float g = acc_g[mb][r], u = acc_u[mb][r];
                float a = g / (1.f + expf(-g)) * u;
                act[((size_t)e * CAP + row) * IDIM + colg] = bf16_bits(a);
            }
        }
    }
}

// ------------- Stage B: y = act@w2^T, scatter out[tok] += w*y ---------------
// grid (32, 64): blockIdx.x = 64-wide N-tile of HDIM, blockIdx.y = expert.
__global__ __launch_bounds__(256) void expert_down_kernel(
    const unsigned short* __restrict__ act, const float* __restrict__ w2,
    const int* __restrict__ cnt, const int* __restrict__ tok_map,
    const float* __restrict__ w_map, float* __restrict__ out)
{
    const int e = blockIdx.y;
    int count = cnt[e]; if (count > CAP) count = CAP;
    if (count == 0) return;
    const int nt0 = blockIdx.x * 64;
    const int tid = threadIdx.x;
    const int lane = tid & 63, wave = tid >> 6;
    const int nl = lane & 15, quad = lane >> 4;

    __shared__ __align__(16) unsigned short a_lds[CAP * 40];
    __shared__ int   tok_sh[CAP];
    __shared__ float wt_sh[CAP];
    tok_sh[tid] = tok_map[e * CAP + tid];   // slots >= count are garbage; guarded below
    wt_sh[tid] = w_map[e * CAP + tid];

    floatx4 acc[16];
    #pragma unroll
    for (int i = 0; i < 16; i++) acc[i] = (floatx4)(0.f);

    const unsigned short* Abase = act + (size_t)e * CAP * IDIM;
    const int nrow = nt0 + wave * 16 + nl;
    const float* B2 = w2 + (size_t)e * HDIM * IDIM + (size_t)nrow * IDIM;

    const int srow = tid >> 2;
    const int scol = (tid & 3) * 8;

    for (int k0 = 0; k0 < IDIM; k0 += 32) {
        #pragma unroll
        for (int p = 0; p < 4; p++) {
            int r = srow + p * 64;
            uint4 val = (r < count)
                ? *reinterpret_cast<const uint4*>(Abase + (size_t)r * IDIM + k0 + scol)
                : make_uint4(0u, 0u, 0u, 0u);
            *reinterpret_cast<uint4*>(&a_lds[r * 40 + scol]) = val;
        }
        const float* bp = B2 + k0 + quad * 8;
        float4 b0 = *reinterpret_cast<const float4*>(bp);
        float4 b1 = *reinterpret_cast<const float4*>(bp + 4);
        short8 bf = pack_bf16x8(b0, b1);
        __syncthreads();
        #pragma unroll
        for (int mb = 0; mb < 16; mb++) {
            if (mb * 16 < count) {
                short8 af = *reinterpret_cast<const short8*>(&a_lds[(mb * 16 + nl) * 40 + quad * 8]);
                acc[mb] = __builtin_amdgcn_mfma_f32_16x16x32_bf16(af, bf, acc[mb], 0, 0, 0);
            }
        }
        __syncthreads();
    }

    const int colg = nt0 + wave * 16 + nl;
    #pragma unroll
    for (int mb = 0; mb < 16; mb++) {
        if (mb * 16 >= count) break;
        #pragma unroll
        for (int r = 0; r < 4; r++) {
            int row = mb * 16 + quad * 4 + r;
            if (row < count) {
                float y = acc[mb][r] * wt_sh[row];
                unsafeAtomicAdd(&out[(size_t)tok_sh[row] * HDIM + colg], y);
            }
        }
    }
}

// ---------------------------------------------------------------------------
extern "C" void kernel_launch(void* const* d_in, const int* in_sizes, int n_in,
                              void* d_out, int out_size, void* d_ws, size_t ws_size,
                              hipStream_t stream) {
    const float* x  = (const float*)d_in[0];   // [1,512,2048]
    const float* gw = (const float*)d_in[1];   // [64,2048]
    const float* w1 = (const float*)d_in[2];   // [64,768,2048]
    const float* w2 = (const float*)d_in[3];   // [64,2048,768]
    const float* w3 = (const float*)d_in[4];   // [64,768,2048]
    float* out = (float*)d_out;                // out [512*2048] ++ logits [512*64]

    // workspace layout (~92.5 MB)
    char* ws = (char*)d_ws;
    int*   cnt     = (int*)ws;                                   // 64 ints
    int*   tok_map = (int*)(ws + 4096);                          // 64*256 ints
    float* w_map   = (float*)(ws + 4096 + 65536);                // 64*256 floats
    unsigned short* xb  = (unsigned short*)(ws + 135168);        // E*CAP*H bf16 = 67.1MB
    unsigned short* act = (unsigned short*)(ws + 135168 + (size_t)NEXP*CAP*HDIM*2); // E*CAP*I bf16

    hipMemsetAsync(cnt, 0, NEXP * sizeof(int), stream);
    hipMemsetAsync(out, 0, (size_t)NTOK * HDIM * sizeof(float), stream);

    router_kernel<<<NTOK, 256, 0, stream>>>(x, gw, out, cnt, tok_map, w_map, xb);

    dim3 gA(IDIM / 64, NEXP);
    expert_gu_kernel<<<gA, 256, 0, stream>>>(xb, w1, w3, cnt, act);

    dim3 gB(HDIM / 64, NEXP);
    expert_down_kernel<<<gB, 256, 0, stream>>>(act, w2, cnt, tok_map, w_map, out);
}